// Round 2
// baseline (301.891 us; speedup 1.0000x reference)
//
#include <hip/hip_runtime.h>

// Problem constants (fixed by reference setup_inputs)
#define BT    16384          // b*t = 4*4096
#define TSEQ  4096           // time steps per batch
#define DM    1024           // d_model
#define EXP   1024           // expanded
#define N1    2048           // 2*EXP
#define KDIM  1024           // GEMM K (both GEMMs)
#define NKT   16             // K-tiles of BK=64
#define EPSV  1e-8f

typedef __bf16 bf16x8 __attribute__((ext_vector_type(8)));
typedef float f32x4 __attribute__((ext_vector_type(4)));
typedef unsigned short u16x8 __attribute__((ext_vector_type(8)));

#define AS1CAST(p) ((__attribute__((address_space(1))) void*)(p))
#define AS3CAST(p) ((__attribute__((address_space(3))) void*)(p))

__device__ __forceinline__ unsigned short f2bf(float f) {
    unsigned int u = __float_as_uint(f);
    u += 0x7fffu + ((u >> 16) & 1u);
    return (unsigned short)(u >> 16);
}

// ---------------------------------------------------------------------------
// fp32 -> bf16 conversion for all three inputs + zero-init of ssq[2*BT],
// all in ONE launch (4 elems/thread).
__global__ __launch_bounds__(256) void k_f2bf3(const float* __restrict__ i0, unsigned short* __restrict__ o0, int n0,
                                               const float* __restrict__ i1, unsigned short* __restrict__ o1, int n1,
                                               const float* __restrict__ i2, unsigned short* __restrict__ o2, int n2,
                                               float* __restrict__ ssq) {
    int i = blockIdx.x * 256 + threadIdx.x;
    const float* in; unsigned short* out;
    if (i < n0)                { in = i0; out = o0; }
    else if (i < n0 + n1)      { in = i1; out = o1; i -= n0; }
    else if (i < n0 + n1 + n2) { in = i2; out = o2; i -= n0 + n1; }
    else {
        i -= n0 + n1 + n2;
        if (i < 2 * BT / 4) ((float4*)ssq)[i] = make_float4(0.f, 0.f, 0.f, 0.f);
        return;
    }
    float4 v = ((const float4*)in)[i];
    ushort4 o;
    o.x = f2bf(v.x); o.y = f2bf(v.y); o.z = f2bf(v.z); o.w = f2bf(v.w);
    ((ushort4*)out)[i] = o;
}

// ---------------------------------------------------------------------------
// bf16 GEMM, C[m,n] = sum_k A[m,k]*B[n,k] + bias[n]  -- 256x256 8-phase template
// (guide 5.5 T3+T4+T2+T5, m201 structure ported to this problem).
// Block 256(M)x256(N), 512 thr = 8 waves as 2(M)x4(N); wave tile 128x64 =
// 8x4 grid of 16x16x32 MFMA (f32x4 acc[8][4] = 128 AGPR).
// K-tile BK=64, split in two K-halves of 32. LDS = 2 parity x 2 khalf x
// 16 KB per operand = 128 KB. 4 phases per K-tile:
//   p0: read A.kh0 frags(8)+B.kh0 nr01(2) | stage A.kh1(T+1) | BAR lgkm0 prio 16MFMA prio BAR
//   p1: read B.kh0 nr23(2)               | stage B.kh1(T+1) | ...
//   p2: read A.kh1(8)+B.kh1 nr01(2)      | stage A.kh0(T+2) | ...
//   p3: read B.kh1 nr23(2)               | stage B.kh0(T+2) | vmcnt(4) BAR
// Counted vmcnt ONCE per K-tile (never 0 in main loop): at p3, everything
// up to B.kh1(T+1) must be landed; the only younger loads are the 4 insts
// of kh0(T+2) -> vmcnt(4). Tail T>=14 uses vmcnt(0) (fewer in flight).
// Region-death audit (formal race-freedom): each stage target was last
// READ >=1 full barrier before the stage issue (e.g. p0 stages A.kh1(T+1)
// over A.kh1(T-1), dead since p2(T-1)'s post-MFMA barrier).
// LDS swizzle (T2): 16-B k-slot phys = klog ^ ((row>>1)&3). Reads: each
// 16-lane group spreads over 8 bank-quads exactly 2-way (2-way = free,
// m136). Staging stays linear-dest global_load_lds; the swizzle is applied
// by pre-permuting the per-thread GLOBAL source k-group
// qS = (t&3) ^ ((t>>3)&3) (both-sides-or-neither, rule #21).
// XCD chunked swizzle: W = (L&7)*(nwg/8) + L>>3 (bijective, nwg%8==0).
// Epilogue: bias + C-store + per-row sum-sq via 4x shfl_xor (16-lane
// reduce), one atomicAdd per output row (no LDS scratch).
template <int BF16_OUT, int NTN>
__device__ __forceinline__ void gemm_body(const unsigned short* __restrict__ A,
                                          const unsigned short* __restrict__ Bw,
                                          const float* __restrict__ bias,
                                          unsigned short* __restrict__ Cb,
                                          float* __restrict__ Cf,
                                          float* __restrict__ ssq,
                                          int N) {
    __shared__ __align__(16) char smem[131072];   // A: 0..64K, B: 64K..128K

    const int tid  = threadIdx.x;
    const int lane = tid & 63;
    const int w    = tid >> 6;       // 0..7
    const int wm   = w >> 2;         // 0..1  (M half)
    const int wn   = w & 3;          // 0..3  (N quarter)
    const int l15  = lane & 15;
    const int l4   = lane >> 4;

    // XCD chunked swizzle (bijective: gridDim.x % 8 == 0 for both GEMMs)
    const int L   = blockIdx.x;
    const int cpx = (NTN * (BT / 256)) >> 3;
    const int W   = (L & 7) * cpx + (L >> 3);
    const int mt  = W / NTN, nt = W % NTN;
    const int row0 = mt * 256, col0 = nt * 256;

    // Staging: half-tile = [256 rows][32 k] = 16 KB = 512 thr x 2 x 16 B.
    // slot s = b*512 + tid -> row = b*128 + (tid>>2), phys k-slot = tid&3;
    // source k-group pre-swizzled: qS = (tid&3) ^ ((tid>>3)&3)  (== phys ^ ((row>>1)&3))
    const int rS = tid >> 2;
    const int qS = (tid & 3) ^ ((tid >> 3) & 3);

    auto stageA = [&](int T2, int kh) {
        const unsigned short* src = A + (size_t)(row0 + rS) * KDIM + T2 * 64 + kh * 32 + qS * 8;
        char* dst = smem + ((T2 & 1) * 32768 + kh * 16384) + tid * 16;
#pragma unroll
        for (int b = 0; b < 2; ++b)
            __builtin_amdgcn_global_load_lds(AS1CAST(src + (size_t)b * 128 * KDIM),
                                             AS3CAST(dst + b * 8192), 16, 0, 0);
    };
    auto stageB = [&](int T2, int kh) {
        const unsigned short* src = Bw + (size_t)(col0 + rS) * KDIM + T2 * 64 + kh * 32 + qS * 8;
        char* dst = smem + (65536 + (T2 & 1) * 32768 + kh * 16384) + tid * 16;
#pragma unroll
        for (int b = 0; b < 2; ++b)
            __builtin_amdgcn_global_load_lds(AS1CAST(src + (size_t)b * 128 * KDIM),
                                             AS3CAST(dst + b * 8192), 16, 0, 0);
    };

    // Fragment read offsets: A-frag(mr,kh): lane l -> row wm*128+mr*16+l15,
    // k-slot phys = l4 ^ ((l15>>1)&3); row stride 64 B.
    const int pslot = (l4 ^ ((l15 >> 1) & 3)) * 16;
    const int aL = (wm * 128 + l15) * 64 + pslot;
    const int bL = (wn * 64 + l15) * 64 + pslot;

    f32x4 acc[8][4] = {};

    // prologue: T0 both halves + T1 kh0 (6 half-tiles, 12 insts)
    stageA(0, 0); stageB(0, 0);
    stageA(0, 1); stageB(0, 1);
    stageA(1, 0); stageB(1, 0);
    asm volatile("s_waitcnt vmcnt(4)" ::: "memory");   // T0 fully landed
    __builtin_amdgcn_s_barrier();

#pragma unroll 1
    for (int T = 0; T < NKT; ++T) {
        const char* Ab = smem + (T & 1) * 32768;
        const char* Bb = smem + 65536 + (T & 1) * 32768;
        bf16x8 aF[8], bF[4];

        // ---- phase 0: kh0, nr 0-1 ----
#pragma unroll
        for (int mr = 0; mr < 8; ++mr) aF[mr] = *(const bf16x8*)(Ab + aL + mr * 1024);
        bF[0] = *(const bf16x8*)(Bb + bL);
        bF[1] = *(const bf16x8*)(Bb + bL + 1024);
        if (T + 1 < NKT) stageA(T + 1, 1);
        __builtin_amdgcn_s_barrier();
        asm volatile("s_waitcnt lgkmcnt(0)" ::: "memory");
        __builtin_amdgcn_s_setprio(1);
#pragma unroll
        for (int mr = 0; mr < 8; ++mr) {
            acc[mr][0] = __builtin_amdgcn_mfma_f32_16x16x32_bf16(aF[mr], bF[0], acc[mr][0], 0, 0, 0);
            acc[mr][1] = __builtin_amdgcn_mfma_f32_16x16x32_bf16(aF[mr], bF[1], acc[mr][1], 0, 0, 0);
        }
        __builtin_amdgcn_s_setprio(0);
        __builtin_amdgcn_s_barrier();

        // ---- phase 1: kh0, nr 2-3 ----
        bF[2] = *(const bf16x8*)(Bb + bL + 2048);
        bF[3] = *(const bf16x8*)(Bb + bL + 3072);
        if (T + 1 < NKT) stageB(T + 1, 1);
        __builtin_amdgcn_s_barrier();
        asm volatile("s_waitcnt lgkmcnt(0)" ::: "memory");
        __builtin_amdgcn_s_setprio(1);
#pragma unroll
        for (int mr = 0; mr < 8; ++mr) {
            acc[mr][2] = __builtin_amdgcn_mfma_f32_16x16x32_bf16(aF[mr], bF[2], acc[mr][2], 0, 0, 0);
            acc[mr][3] = __builtin_amdgcn_mfma_f32_16x16x32_bf16(aF[mr], bF[3], acc[mr][3], 0, 0, 0);
        }
        __builtin_amdgcn_s_setprio(0);
        __builtin_amdgcn_s_barrier();

        // ---- phase 2: kh1, nr 0-1 ----
#pragma unroll
        for (int mr = 0; mr < 8; ++mr) aF[mr] = *(const bf16x8*)(Ab + 16384 + aL + mr * 1024);
        bF[0] = *(const bf16x8*)(Bb + 16384 + bL);
        bF[1] = *(const bf16x8*)(Bb + 16384 + bL + 1024);
        if (T + 2 < NKT) stageA(T + 2, 0);
        __builtin_amdgcn_s_barrier();
        asm volatile("s_waitcnt lgkmcnt(0)" ::: "memory");
        __builtin_amdgcn_s_setprio(1);
#pragma unroll
        for (int mr = 0; mr < 8; ++mr) {
            acc[mr][0] = __builtin_amdgcn_mfma_f32_16x16x32_bf16(aF[mr], bF[0], acc[mr][0], 0, 0, 0);
            acc[mr][1] = __builtin_amdgcn_mfma_f32_16x16x32_bf16(aF[mr], bF[1], acc[mr][1], 0, 0, 0);
        }
        __builtin_amdgcn_s_setprio(0);
        __builtin_amdgcn_s_barrier();

        // ---- phase 3: kh1, nr 2-3 ----
        bF[2] = *(const bf16x8*)(Bb + 16384 + bL + 2048);
        bF[3] = *(const bf16x8*)(Bb + 16384 + bL + 3072);
        if (T + 2 < NKT) stageB(T + 2, 0);
        __builtin_amdgcn_s_barrier();
        asm volatile("s_waitcnt lgkmcnt(0)" ::: "memory");
        __builtin_amdgcn_s_setprio(1);
#pragma unroll
        for (int mr = 0; mr < 8; ++mr) {
            acc[mr][2] = __builtin_amdgcn_mfma_f32_16x16x32_bf16(aF[mr], bF[2], acc[mr][2], 0, 0, 0);
            acc[mr][3] = __builtin_amdgcn_mfma_f32_16x16x32_bf16(aF[mr], bF[3], acc[mr][3], 0, 0, 0);
        }
        __builtin_amdgcn_s_setprio(0);
        // all of T+1 landed; only kh0(T+2)'s 4 insts may remain in flight
        if (T < NKT - 2) asm volatile("s_waitcnt vmcnt(4)" ::: "memory");
        else             asm volatile("s_waitcnt vmcnt(0)" ::: "memory");
        __builtin_amdgcn_s_barrier();
    }

    // ---- epilogue ----
    // C/D 16x16: col = l15 (+nr*16 +wn*64), row = l4*4 + reg (+mr*16 +wm*128)
    const int c0 = col0 + wn * 64 + l15;
    float bsv[4];
#pragma unroll
    for (int nr = 0; nr < 4; ++nr) bsv[nr] = bias[c0 + nr * 16];

#pragma unroll
    for (int mr = 0; mr < 8; ++mr) {
#pragma unroll
        for (int reg = 0; reg < 4; ++reg) {
            const int gm = row0 + wm * 128 + mr * 16 + l4 * 4 + reg;
            const size_t base = (size_t)gm * N + c0;
            float p = 0.f;
#pragma unroll
            for (int nr = 0; nr < 4; ++nr) {
                float v = acc[mr][nr][reg] + bsv[nr];
                p += v * v;
                if (BF16_OUT) Cb[base + nr * 16] = f2bf(v);
                else          Cf[base + nr * 16] = v;
            }
            // reduce p over the 16-lane group (cols of this row)
            p += __shfl_xor(p, 1);
            p += __shfl_xor(p, 2);
            p += __shfl_xor(p, 4);
            p += __shfl_xor(p, 8);
            if (l15 == 0) atomicAdd(&ssq[gm], p);
        }
    }
}

__global__ __launch_bounds__(512, 2) void k_gemm_in(const unsigned short* __restrict__ A,
                                                    const unsigned short* __restrict__ Bw,
                                                    const float* __restrict__ bias,
                                                    unsigned short* __restrict__ Cb,
                                                    float* __restrict__ ssq) {
    gemm_body<1, 8>(A, Bw, bias, Cb, nullptr, ssq, N1);
}

__global__ __launch_bounds__(512, 2) void k_gemm_out(const unsigned short* __restrict__ A,
                                                     const unsigned short* __restrict__ Bw,
                                                     const float* __restrict__ bias,
                                                     float* __restrict__ Cf,
                                                     float* __restrict__ ssq) {
    gemm_body<0, 4>(A, Bw, bias, nullptr, Cf, ssq, DM);
}

// ---------------------------------------------------------------------------
// RMSNorm(z) -> split x|v -> depthwise conv(K=3, same, per-batch) -> gate
// 2 tokens / block; 128 threads/token; 8 channels/thread.
__global__ __launch_bounds__(256) void k_conv_gate(const unsigned short* __restrict__ z,
                                                   const float* __restrict__ ssq1,
                                                   const float* __restrict__ inw,
                                                   const float* __restrict__ cw,
                                                   const float* __restrict__ cb,
                                                   unsigned short* __restrict__ g) {
    const int tok = blockIdx.x * 2 + (threadIdx.x >> 7);
    const int e8  = (threadIdx.x & 127) * 8;
    const int t   = tok & (TSEQ - 1);

    const float rs0 = rsqrtf(ssq1[tok] * (1.0f / N1) + EPSV);
    const int tm = (t > 0) ? tok - 1 : tok;
    const int tp = (t < TSEQ - 1) ? tok + 1 : tok;
    const float rsm = (t > 0) ? rsqrtf(ssq1[tm] * (1.0f / N1) + EPSV) : 0.0f;
    const float rsp = (t < TSEQ - 1) ? rsqrtf(ssq1[tp] * (1.0f / N1) + EPSV) : 0.0f;

    bf16x8 xm = *(const bf16x8*)(z + (size_t)tm * N1 + e8);
    bf16x8 x0 = *(const bf16x8*)(z + (size_t)tok * N1 + e8);
    bf16x8 xp = *(const bf16x8*)(z + (size_t)tp * N1 + e8);
    bf16x8 vv = *(const bf16x8*)(z + (size_t)tok * N1 + EXP + e8);

    u16x8 ov;
#pragma unroll
    for (int p = 0; p < 8; ++p) {
        const int e = e8 + p;
        const float we  = inw[e];
        const float wvv = inw[EXP + e];
        const float w0 = cw[e * 3], w1 = cw[e * 3 + 1], w2 = cw[e * 3 + 2];
        float y = w0 * ((float)xm[p] * rsm * we)
                + w1 * ((float)x0[p] * rs0 * we)
                + w2 * ((float)xp[p] * rsp * we)
                + cb[e];
        float vn = (float)vv[p] * rs0 * wvv;
        ov[p] = f2bf(vn * y);
    }
    *(u16x8*)(g + (size_t)tok * EXP + e8) = ov;
}

// ---------------------------------------------------------------------------
// Final RMSNorm scale in place on fp32 output: out *= rsqrt(mean)*w
__global__ __launch_bounds__(256) void k_outnorm(float* __restrict__ o,
                                                 const float* __restrict__ ssq2,
                                                 const float* __restrict__ onw) {
    const int idx = blockIdx.x * 256 + threadIdx.x;   // one float4
    const int tok = idx >> 8;                         // 256 float4 per token
    const int d4  = (idx & 255) * 4;
    const float rs = rsqrtf(ssq2[tok] * (1.0f / DM) + EPSV);
    float4 v = ((float4*)o)[idx];
    float4 w = *(const float4*)(onw + d4);
    v.x *= rs * w.x; v.y *= rs * w.y; v.z *= rs * w.z; v.w *= rs * w.w;
    ((float4*)o)[idx] = v;
}

// ---------------------------------------------------------------------------
extern "C" void kernel_launch(void* const* d_in, const int* in_sizes, int n_in,
                              void* d_out, int out_size, void* d_ws, size_t ws_size,
                              hipStream_t stream) {
    const float* u     = (const float*)d_in[0];
    const float* W_in  = (const float*)d_in[1];
    const float* b_in  = (const float*)d_in[2];
    const float* inw   = (const float*)d_in[3];
    const float* cw    = (const float*)d_in[4];
    const float* cb    = (const float*)d_in[5];
    const float* W_out = (const float*)d_in[6];
    const float* b_out = (const float*)d_in[7];
    const float* onw   = (const float*)d_in[8];
    float* out = (float*)d_out;

    char* ws = (char*)d_ws;
    unsigned short* u_bf    = (unsigned short*)ws; ws += (size_t)BT * DM * 2;     // 32 MB
    unsigned short* Win_bf  = (unsigned short*)ws; ws += (size_t)N1 * DM * 2;     //  4 MB
    unsigned short* Wout_bf = (unsigned short*)ws; ws += (size_t)DM * EXP * 2;    //  2 MB
    unsigned short* z_bf    = (unsigned short*)ws; ws += (size_t)BT * N1 * 2;     // 64 MB
    unsigned short* g_bf    = (unsigned short*)ws; ws += (size_t)BT * EXP * 2;    // 32 MB
    float* ssq1 = (float*)ws; ws += (size_t)BT * 4;
    float* ssq2 = (float*)ws; ws += (size_t)BT * 4;   // contiguous after ssq1

    const int n0 = BT * DM / 4, n1c = N1 * DM / 4, n2c = DM * EXP / 4;
    const int ntot = n0 + n1c + n2c + 2 * BT / 4;
    k_f2bf3<<<(ntot + 255) / 256, 256, 0, stream>>>(u, u_bf, n0,
                                                    W_in, Win_bf, n1c,
                                                    W_out, Wout_bf, n2c,
                                                    ssq1);

    k_gemm_in<<<(BT / 256) * (N1 / 256), 512, 0, stream>>>(u_bf, Win_bf, b_in, z_bf, ssq1);

    k_conv_gate<<<BT / 2, 256, 0, stream>>>(z_bf, ssq1, inw, cw, cb, g_bf);

    k_gemm_out<<<(BT / 256) * (DM / 256), 512, 0, stream>>>(g_bf, Wout_bf, b_out, out, ssq2);

    k_outnorm<<<BT, 256, 0, stream>>>(out, ssq2, onw);

    (void)in_sizes; (void)n_in; (void)out_size; (void)ws_size;
}